// Round 19
// baseline (133.363 us; speedup 1.0000x reference)
//
#include <hip/hip_runtime.h>
#include <math.h>

#define NT 32768
#define DIM 2048
#define NE 64
#define RSCALE 2.5f
#define REPS 1e-20f
#define KC 32
#define NCH (DIM / KC)
#define TOK 128                 // tokens per block
#define NHW 16                  // half-windows (128 K each)
#define HW_BYTES 49152          // 4 chunks x 12288 B image

// LDS: buf[2][49152] at 0; bsf f32[64] at 98304. scf f32[128][65] aliases buf0.
#define BS_OFF 98304
#define ARENA 98560

typedef const __attribute__((address_space(1))) void GV;
typedef __attribute__((address_space(3))) void LV;
typedef __attribute__((ext_vector_type(8))) short short8x;
typedef __attribute__((ext_vector_type(4))) float f32x4;
typedef __attribute__((ext_vector_type(4))) unsigned int uint4x;

// W limb image, pre-decomposed + pre-swizzled per chunk (12 KB each), contiguous
// across chunks -> half-window hw is one contiguous 48 KB run. (R14-verified bytes)
__device__ __align__(16) char WImg[NCH][3 * 4096];

#define PACKHI(odd, even) __builtin_amdgcn_perm((odd), (even), 0x07060302u)

__device__ __forceinline__ void decomp4(f32x4 x, unsigned int o[6]) {
    unsigned int u0 = __float_as_uint(x.x), u1 = __float_as_uint(x.y);
    unsigned int u2 = __float_as_uint(x.z), u3 = __float_as_uint(x.w);
    o[0] = PACKHI(u1, u0); o[1] = PACKHI(u3, u2);
    float r0 = x.x - __uint_as_float(u0 & 0xffff0000u);
    float r1 = x.y - __uint_as_float(u1 & 0xffff0000u);
    float r2 = x.z - __uint_as_float(u2 & 0xffff0000u);
    float r3 = x.w - __uint_as_float(u3 & 0xffff0000u);
    unsigned int v0 = __float_as_uint(r0), v1 = __float_as_uint(r1);
    unsigned int v2 = __float_as_uint(r2), v3 = __float_as_uint(r3);
    o[2] = PACKHI(v1, v0); o[3] = PACKHI(v3, v2);
    float s0 = r0 - __uint_as_float(v0 & 0xffff0000u);
    float s1 = r1 - __uint_as_float(v1 & 0xffff0000u);
    float s2 = r2 - __uint_as_float(v2 & 0xffff0000u);
    float s3 = r3 - __uint_as_float(v3 & 0xffff0000u);
    o[4] = PACKHI(__float_as_uint(s1), __float_as_uint(s0));
    o[5] = PACKHI(__float_as_uint(s3), __float_as_uint(s2));
}

__device__ __forceinline__ void decomp8(f32x4 a, f32x4 b,
                                        short8x* f0, short8x* f1, short8x* f2) {
    unsigned int oa[6], ob[6];
    decomp4(a, oa); decomp4(b, ob);
    uint4x t0 = {oa[0], oa[1], ob[0], ob[1]};
    uint4x t1 = {oa[2], oa[3], ob[2], ob[3]};
    uint4x t2 = {oa[4], oa[5], ob[4], ob[5]};
    *f0 = __builtin_bit_cast(short8x, t0);
    *f1 = __builtin_bit_cast(short8x, t1);
    *f2 = __builtin_bit_cast(short8x, t2);
}

// pre-pass: decompose W once into the image layout. 64 blocks x 256. (R14-verified)
__global__ void prep_w_kernel(const float* __restrict__ W) {
    const int ch = blockIdx.x;
    const int tid = threadIdx.x;
    const int srow = tid >> 2;          // expert row 0..63
    const int sq   = tid & 3;           // k-octet 0..3
    const float* src = W + (size_t)srow * DIM + ch * KC + sq * 8;
    f32x4 lo = *(const f32x4*)src;
    f32x4 hi = *(const f32x4*)(src + 4);
    short8x f0, f1, f2;
    decomp8(lo, hi, &f0, &f1, &f2);
    const int soff = srow * 64 + ((sq ^ ((srow >> 1) & 3)) << 4);
    *(short8x*)&WImg[ch][0 * 4096 + soff] = f0;
    *(short8x*)&WImg[ch][1 * 4096 + soff] = f1;
    *(short8x*)&WImg[ch][2 * 4096 + soff] = f2;
}

#define SB __builtin_amdgcn_sched_barrier(0)

// T4 counted barrier: DMA(next half-window) = 6 oldest vm ops must land; the 8 H
// register loads issued after them stay IN FLIGHT across the barrier (compiler's
// own vmcnt(14) before next phase's decomp covers them). No vmcnt(0) in the loop.
#define CBARRIER() do { \
    SB; \
    asm volatile("s_waitcnt vmcnt(8) lgkmcnt(0)" ::: "memory"); \
    __builtin_amdgcn_s_barrier(); \
    SB; \
} while (0)

// DMA one half-window's 48 KB image into LDS buffer (6 x 8 KB rounds, zero VALU)
#define DMA(HW_, BUFO) do { \
    const char* s_ = wimgf + (size_t)(HW_) * HW_BYTES + (tid << 4); \
    _Pragma("unroll") \
    for (int r_ = 0; r_ < 6; ++r_) \
        __builtin_amdgcn_global_load_lds((GV*)(s_ + r_ * 8192), \
            (LV*)(arena + (BUFO) + r_ * 8192 + wlbase), 16, 0, 0); \
} while (0)

// load the 4 H-octets (f32x8) of half-window HW_
#define HLOAD(HR, HW_) do { \
    _Pragma("unroll") \
    for (int c_ = 0; c_ < 4; ++c_) { \
        const float* p_ = hsrc + ((HW_) * 4 + c_) * KC; \
        HR[c_][0] = *(const f32x4*)p_; \
        HR[c_][1] = *(const f32x4*)(p_ + 4); \
    } \
} while (0)

// one half-window of compute: 4 chunks x (decomp + 4 et x (3 ds_read + 6 MFMA)).
// Per-(t,e) limb-product order identical to all passing kernels. T5: setprio wrap.
#define COMPUTE(BUFO, HR) do { \
    __builtin_amdgcn_s_setprio(1); \
    _Pragma("unroll") \
    for (int c_ = 0; c_ < 4; ++c_) { \
        short8x a0, a1, a2; \
        decomp8(HR[c_][0], HR[c_][1], &a0, &a1, &a2); \
        const char* cb_ = arena + (BUFO) + c_ * 12288; \
        _Pragma("unroll") \
        for (int et = 0; et < 4; ++et) { \
            const int e_ = et * 16 + l15; \
            const int ro_ = e_ * 64 + ((g ^ ((e_ >> 1) & 3)) << 4); \
            short8x b0 = *(const short8x*)(cb_ + 0 * 4096 + ro_); \
            short8x b1 = *(const short8x*)(cb_ + 1 * 4096 + ro_); \
            short8x b2 = *(const short8x*)(cb_ + 2 * 4096 + ro_); \
            Cm[et] = __builtin_amdgcn_mfma_f32_16x16x32_bf16(a0, b0, Cm[et], 0, 0, 0); \
            Cc[et] = __builtin_amdgcn_mfma_f32_16x16x32_bf16(a1, b0, Cc[et], 0, 0, 0); \
            Cc[et] = __builtin_amdgcn_mfma_f32_16x16x32_bf16(a2, b0, Cc[et], 0, 0, 0); \
            Cc[et] = __builtin_amdgcn_mfma_f32_16x16x32_bf16(a0, b1, Cc[et], 0, 0, 0); \
            Cc[et] = __builtin_amdgcn_mfma_f32_16x16x32_bf16(a1, b1, Cc[et], 0, 0, 0); \
            Cc[et] = __builtin_amdgcn_mfma_f32_16x16x32_bf16(a0, b2, Cc[et], 0, 0, 0); \
        } \
    } \
    __builtin_amdgcn_s_setprio(0); \
} while (0)

#define DRAIN do { \
    _Pragma("unroll") \
    for (int et = 0; et < 4; ++et) { \
        _Pragma("unroll") \
        for (int r = 0; r < 4; ++r) \
            md[et][r] += (double)Cm[et][r] + (double)Cc[et][r]; \
        Cm[et] = (f32x4)0.0f; Cc[et] = (f32x4)0.0f; \
    } \
} while (0)

// 256 blocks x 512 threads (8 waves, 1 block/CU). Block = 128 tok x 64 exp; wave w
// owns tokens w*16..w*16+15 x ALL 64 experts. W image double-buffered per 128-K
// half-window via DMA; counted vmcnt(8) barriers (T4) keep the H stream in flight
// across barriers; setprio around compute (T5). 2 barriers per half-window.
__global__ __launch_bounds__(512, 1) void router_kernel(
    const float* __restrict__ H,
    const float* __restrict__ B,
    float* __restrict__ out)
{
    __shared__ __align__(16) char arena[ARENA];
    float* bsf = (float*)(arena + BS_OFF);
    float* scf = (float*)(arena);               // epilogue alias over buf0

    const int tid  = threadIdx.x;
    const int lane = tid & 63;
    const int w    = __builtin_amdgcn_readfirstlane(tid >> 6);   // 0..7
    const int l15  = lane & 15, g = lane >> 4;
    const size_t tb = (size_t)blockIdx.x * TOK;
    const char* wimgf = &WImg[0][0];
    const int wlbase = w * 1024;                // wave-uniform LDS base within round

    if (tid < NE) bsf[tid] = B[tid];

    // lane l: H[token = tb + w*16 + (l&15)][ch*32 + (l>>4)*8 .. +7]
    const float* hsrc = H + (tb + (size_t)(w * 16 + l15)) * DIM + g * 8;

    f32x4 Cm[4], Cc[4];
    double md[4][4];
    #pragma unroll
    for (int et = 0; et < 4; ++et) {
        Cm[et] = (f32x4)0.0f; Cc[et] = (f32x4)0.0f;
        #pragma unroll
        for (int r = 0; r < 4; ++r) md[et][r] = 0.0;
    }

    f32x4 hA[4][2], hB[4][2];

    // prologue: DMA hw0 -> buf0; H of hw0 -> hA; full drain once
    DMA(0, 0);
    HLOAD(hA, 0);
    __syncthreads();                            // vmcnt(0): buf0 + hA ready

    for (int hw = 0; hw < NHW; hw += 2) {
        // phase hw (even): issue {DMA(hw+1)->buf1, H(hw+1)->hB}; compute buf0
        DMA(hw + 1, HW_BYTES);
        HLOAD(hB, hw + 1);
        SB;                                     // pin issue bundle before compute
        COMPUTE(0, hA);
        CBARRIER();                             // DMA(hw+1) landed; hB in flight

        // phase hw+1 (odd): issue {DMA(hw+2)->buf0, H(hw+2)->hA}; compute buf1
        if (hw + 2 < NHW) {
            DMA(hw + 2, 0);
            HLOAD(hA, hw + 2);
        }
        SB;
        COMPUTE(HW_BYTES, hB);
        DRAIN;                                  // global chunks 8g+7 boundary
        CBARRIER();                             // DMA(hw+2) landed; hA in flight
    }

    __syncthreads();                            // drain everything before aliasing

    // sigmoid scores -> scf (aliases buf0)
    #pragma unroll
    for (int et = 0; et < 4; ++et)
        #pragma unroll
        for (int r = 0; r < 4; ++r) {
            float logit = (float)md[et][r];
            float s = 1.0f / (1.0f + expf(-logit));
            int t = w * 16 + g * 4 + r;
            int e = et * 16 + l15;
            scf[t * 65 + e] = s;
        }
    __syncthreads();

    // grouped top-k, one token per active thread (128 tokens over 8 waves)
    if ((tid & 3) == 0) {
        const int t = tid >> 2;
        const float* sc = &scf[t * 65];
        float gs[8];
        #pragma unroll
        for (int gg = 0; gg < 8; ++gg) {
            float m1 = -1e30f, m2 = -1e30f;
            #pragma unroll
            for (int j = 0; j < 8; ++j) {
                float v = sc[gg * 8 + j] + bsf[gg * 8 + j];
                if (v > m1) { m2 = m1; m1 = v; }
                else if (v > m2) { m2 = v; }
            }
            gs[gg] = m1 + m2;
        }
        unsigned gmask = 0;
        for (int i = 0; i < 4; ++i) {
            float best = -1e30f; int bg = 0;
            for (int gg = 0; gg < 8; ++gg)
                if (!((gmask >> gg) & 1u) && gs[gg] > best) { best = gs[gg]; bg = gg; }
            gmask |= 1u << bg;
        }
        unsigned long long picked = 0ull;
        int   idxs[8];
        float wts[8];
        float wsum = 0.0f;
        for (int i = 0; i < 8; ++i) {
            float best = -1e30f; int bi = 0;
            for (int e = 0; e < 64; ++e) {
                if ((picked >> e) & 1ull) continue;
                float v = ((gmask >> (e >> 3)) & 1u) ? (sc[e] + bsf[e]) : 0.0f;
                if (v > best) { best = v; bi = e; }
            }
            picked |= 1ull << bi;
            idxs[i] = bi;
            wts[i] = sc[bi];
            wsum += sc[bi];
        }
        const float scale = RSCALE / (wsum + REPS);
        const size_t token = tb + t;
        #pragma unroll
        for (int i = 0; i < 8; ++i) {
            out[token * 8 + i] = (float)idxs[i];
            out[(size_t)NT * 8 + token * 8 + i] = wts[i] * scale;
        }
    }
}

extern "C" void kernel_launch(void* const* d_in, const int* in_sizes, int n_in,
                              void* d_out, int out_size, void* d_ws, size_t ws_size,
                              hipStream_t stream) {
    (void)in_sizes; (void)n_in; (void)out_size; (void)d_ws; (void)ws_size;
    const float* H = (const float*)d_in[0];
    const float* W = (const float*)d_in[1];
    const float* B = (const float*)d_in[2];
    float* out = (float*)d_out;
    prep_w_kernel<<<dim3(NCH), dim3(256), 0, stream>>>(W);
    router_kernel<<<dim3(NT / TOK), dim3(512), 0, stream>>>(H, B, out);
}

// Round 20
// 123.420 us; speedup vs baseline: 1.0806x; 1.0806x over previous
//
#include <hip/hip_runtime.h>
#include <math.h>

#define NT 32768
#define DIM 2048
#define NE 64
#define RSCALE 2.5f
#define REPS 1e-20f
#define KC 32
#define NCH (DIM / KC)
#define TOK 64

// LDS arena (bytes):
//   HL[2][3][64 tok][4 slots x 16B]  : 0     .. 24575   (H bf16 limb planes, dbuf)
//   WL[2][3][64 exp][4 slots x 16B]  : 24576 .. 49151   (W bf16 limb planes, dbuf)
//   Bs[64] f32                       : 49152 .. 49407
//   Sc[64][65] f32                   : alias at 0 (epilogue only)
#define HL_BUF 12288
#define WL_OFF 24576
#define BS_OFF 49152
#define ARENA 49408

typedef const __attribute__((address_space(1))) void GV;
typedef __attribute__((address_space(3))) void LV;
typedef __attribute__((ext_vector_type(8))) short short8x;
typedef __attribute__((ext_vector_type(4))) float f32x4;
typedef __attribute__((ext_vector_type(4))) unsigned int uint4x;

// W limb image, pre-decomposed and pre-swizzled: per chunk a 12 KB block that is
// byte-identical to what the R9 kernel's W STAGE_WRITE produced in LDS.
__device__ __align__(16) char WImg[NCH][3 * 4096];

// pack hi16 of two fp32 into one dword (low half = even element)
#define PACKHI(odd, even) __builtin_amdgcn_perm((odd), (even), 0x07060302u)

__device__ __forceinline__ void decomp4(f32x4 x, unsigned int o[6]) {
    unsigned int u0 = __float_as_uint(x.x), u1 = __float_as_uint(x.y);
    unsigned int u2 = __float_as_uint(x.z), u3 = __float_as_uint(x.w);
    o[0] = PACKHI(u1, u0); o[1] = PACKHI(u3, u2);
    float r0 = x.x - __uint_as_float(u0 & 0xffff0000u);
    float r1 = x.y - __uint_as_float(u1 & 0xffff0000u);
    float r2 = x.z - __uint_as_float(u2 & 0xffff0000u);
    float r3 = x.w - __uint_as_float(u3 & 0xffff0000u);
    unsigned int v0 = __float_as_uint(r0), v1 = __float_as_uint(r1);
    unsigned int v2 = __float_as_uint(r2), v3 = __float_as_uint(r3);
    o[2] = PACKHI(v1, v0); o[3] = PACKHI(v3, v2);
    float s0 = r0 - __uint_as_float(v0 & 0xffff0000u);
    float s1 = r1 - __uint_as_float(v1 & 0xffff0000u);
    float s2 = r2 - __uint_as_float(v2 & 0xffff0000u);
    float s3 = r3 - __uint_as_float(v3 & 0xffff0000u);
    o[4] = PACKHI(__float_as_uint(s1), __float_as_uint(s0));
    o[5] = PACKHI(__float_as_uint(s3), __float_as_uint(s2));
}

__device__ __forceinline__ void decomp8(f32x4 a, f32x4 b,
                                        short8x* f0, short8x* f1, short8x* f2) {
    unsigned int oa[6], ob[6];
    decomp4(a, oa); decomp4(b, ob);
    uint4x t0 = {oa[0], oa[1], ob[0], ob[1]};
    uint4x t1 = {oa[2], oa[3], ob[2], ob[3]};
    uint4x t2 = {oa[4], oa[5], ob[4], ob[5]};
    *f0 = __builtin_bit_cast(short8x, t0);
    *f1 = __builtin_bit_cast(short8x, t1);
    *f2 = __builtin_bit_cast(short8x, t2);
}

// pre-pass: decompose W once into the LDS-image layout (same limb values and same
// swizzled slot bytes as the R9 kernel's in-loop W staging). 64 blocks x 256.
__global__ void prep_w_kernel(const float* __restrict__ W) {
    const int ch = blockIdx.x;
    const int tid = threadIdx.x;
    const int srow = tid >> 2;          // expert row 0..63
    const int sq   = tid & 3;           // k-octet 0..3
    const float* src = W + (size_t)srow * DIM + ch * KC + sq * 8;
    f32x4 lo = *(const f32x4*)src;
    f32x4 hi = *(const f32x4*)(src + 4);
    short8x f0, f1, f2;
    decomp8(lo, hi, &f0, &f1, &f2);
    const int soff = srow * 64 + ((sq ^ ((srow >> 1) & 3)) << 4);
    *(short8x*)&WImg[ch][0 * 4096 + soff] = f0;
    *(short8x*)&WImg[ch][1 * 4096 + soff] = f1;
    *(short8x*)&WImg[ch][2 * 4096 + soff] = f2;
}

// H-only register staging (depth-2)
#define STAGE_ISSUE(HA, HB, KOFF) do { \
    HA = *(const f32x4*)(hgsrc + (KOFF)); \
    HB = *(const f32x4*)(hgsrc + (KOFF) + 4); \
} while (0)

#define STAGE_WRITE_H(HA, HB, PN) do { \
    short8x f0_, f1_, f2_; \
    decomp8(HA, HB, &f0_, &f1_, &f2_); \
    *(short8x*)(arena + (PN) * HL_BUF + 0 * 4096 + soff) = f0_; \
    *(short8x*)(arena + (PN) * HL_BUF + 1 * 4096 + soff) = f1_; \
    *(short8x*)(arena + (PN) * HL_BUF + 2 * 4096 + soff) = f2_; \
} while (0)

// W staging: direct L2 -> LDS DMA of the pre-baked image (zero VALU, zero ds_write).
// LDS dest base is wave-uniform; HW writes base + lane*16; global src is per-lane.
#define WSTAGE(CHN, PN) do { \
    const char* ws_ = WImg[(CHN)]; \
    __builtin_amdgcn_global_load_lds((GV*)(ws_ + 0 * 4096 + wgofs), \
        (LV*)(arena + WL_OFF + (PN) * HL_BUF + 0 * 4096 + wlofs), 16, 0, 0); \
    __builtin_amdgcn_global_load_lds((GV*)(ws_ + 1 * 4096 + wgofs), \
        (LV*)(arena + WL_OFF + (PN) * HL_BUF + 1 * 4096 + wlofs), 16, 0, 0); \
    __builtin_amdgcn_global_load_lds((GV*)(ws_ + 2 * 4096 + wgofs), \
        (LV*)(arena + WL_OFF + (PN) * HL_BUF + 2 * 4096 + wlofs), 16, 0, 0); \
} while (0)

// wave = 32 tok x 32 exp = 2x2 of 16x16 tiles; 12 b128 reads feed 24 MFMAs.
// Per-tile MFMA order identical to the passing kernels (bit-identical logits).
#define COMPUTE(P) do { \
    const char* hb = arena + (P) * HL_BUF; \
    const char* wb = arena + WL_OFF + (P) * HL_BUF; \
    short8x a0[2], a1[2], a2[2]; \
    _Pragma("unroll") \
    for (int tt = 0; tt < 2; ++tt) { \
        const int t_ = wr * 32 + tt * 16 + l15; \
        const int ro_ = t_ * 64 + ((g ^ ((t_ >> 1) & 3)) << 4); \
        a0[tt] = *(const short8x*)(hb + 0 * 4096 + ro_); \
        a1[tt] = *(const short8x*)(hb + 1 * 4096 + ro_); \
        a2[tt] = *(const short8x*)(hb + 2 * 4096 + ro_); \
    } \
    _Pragma("unroll") \
    for (int et = 0; et < 2; ++et) { \
        const int e_ = wc * 32 + et * 16 + l15; \
        const int ro_ = e_ * 64 + ((g ^ ((e_ >> 1) & 3)) << 4); \
        short8x b0 = *(const short8x*)(wb + 0 * 4096 + ro_); \
        short8x b1 = *(const short8x*)(wb + 1 * 4096 + ro_); \
        short8x b2 = *(const short8x*)(wb + 2 * 4096 + ro_); \
        _Pragma("unroll") \
        for (int tt = 0; tt < 2; ++tt) { \
            Cm[tt][et] = __builtin_amdgcn_mfma_f32_16x16x32_bf16(a0[tt], b0, Cm[tt][et], 0, 0, 0); \
            Cc[tt][et] = __builtin_amdgcn_mfma_f32_16x16x32_bf16(a1[tt], b0, Cc[tt][et], 0, 0, 0); \
            Cc[tt][et] = __builtin_amdgcn_mfma_f32_16x16x32_bf16(a2[tt], b0, Cc[tt][et], 0, 0, 0); \
            Cc[tt][et] = __builtin_amdgcn_mfma_f32_16x16x32_bf16(a0[tt], b1, Cc[tt][et], 0, 0, 0); \
            Cc[tt][et] = __builtin_amdgcn_mfma_f32_16x16x32_bf16(a1[tt], b1, Cc[tt][et], 0, 0, 0); \
            Cc[tt][et] = __builtin_amdgcn_mfma_f32_16x16x32_bf16(a0[tt], b2, Cc[tt][et], 0, 0, 0); \
        } \
    } \
} while (0)

#define DRAIN do { \
    _Pragma("unroll") \
    for (int tt = 0; tt < 2; ++tt) \
        _Pragma("unroll") \
        for (int et = 0; et < 2; ++et) { \
            _Pragma("unroll") \
            for (int r = 0; r < 4; ++r) \
                md[tt][et][r] += (double)Cm[tt][et][r] + (double)Cc[tt][et][r]; \
            Cm[tt][et] = (f32x4)0.0f; Cc[tt][et] = (f32x4)0.0f; \
        } \
} while (0)

// 512 blocks x 256 threads (4 waves). R9 structure: wave = 32x32 output, dbuf LDS,
// one barrier per chunk. W limbs arrive via global_load_lds from the pre-baked image
// (no W decompose, no W ds_writes in-loop); H staged in registers + decomposed once.
__global__ __launch_bounds__(256, 2) void router_kernel(
    const float* __restrict__ H,
    const float* __restrict__ B,
    float* __restrict__ out)
{
    __shared__ __align__(16) char arena[ARENA];
    float* bsf = (float*)(arena + BS_OFF);
    float* scf = (float*)(arena);

    const int tid  = threadIdx.x;
    const int lane = tid & 63;
    const int w    = __builtin_amdgcn_readfirstlane(tid >> 6);
    const int l15  = lane & 15, g = lane >> 4;
    const size_t tb = (size_t)blockIdx.x * TOK;

    if (tid < NE) bsf[tid] = B[tid];

    // H staging role: token row = tid>>2 (0..63), k-octet = tid&3
    const int srow = tid >> 2;
    const int sq   = tid & 3;
    const float* hgsrc = H + (tb + (size_t)srow) * DIM + sq * 8;
    const int soff = srow * 64 + ((sq ^ ((srow >> 1) & 3)) << 4);

    // W staging addresses: per-lane global offset, wave-uniform LDS offset
    const int wgofs = tid * 16;
    const int wlofs = w * 1024;

    // compute role: wave quadrant (32 tok x 32 exp)
    const int wr = w & 1, wc = w >> 1;

    f32x4 Cm[2][2], Cc[2][2];
    double md[2][2][4];
    #pragma unroll
    for (int tt = 0; tt < 2; ++tt)
        #pragma unroll
        for (int et = 0; et < 2; ++et) {
            Cm[tt][et] = (f32x4)0.0f; Cc[tt][et] = (f32x4)0.0f;
            #pragma unroll
            for (int r = 0; r < 4; ++r) md[tt][et][r] = 0.0;
        }

    f32x4 hA0, hA1, hB0, hB1;

    // prologue: W ch0 -> buf0 (DMA); H ch0 regs -> write buf0; H ch1 regs
    WSTAGE(0, 0);
    STAGE_ISSUE(hA0, hA1, 0);
    STAGE_WRITE_H(hA0, hA1, 0);
    STAGE_ISSUE(hB0, hB1, KC);
    __syncthreads();

    for (int chb = 0; chb < NCH; chb += 2) {
        // even chunk chb: read buf0; stage ch+1 -> buf1
        WSTAGE(chb + 1, 1);
        if (chb + 2 < NCH) STAGE_ISSUE(hA0, hA1, (chb + 2) * KC);
        COMPUTE(0);
        STAGE_WRITE_H(hB0, hB1, 1);
        __syncthreads();

        // odd chunk chb+1: read buf1; stage ch+2 -> buf0
        if (chb + 2 < NCH) {
            WSTAGE(chb + 2, 0);
            STAGE_ISSUE(hB0, hB1, (chb + 3 < NCH) ? (chb + 3) * KC : (chb + 2) * KC);
        }
        COMPUTE(1);
        if (chb + 2 < NCH) STAGE_WRITE_H(hA0, hA1, 0);
        if (((chb + 1) & 7) == 7) DRAIN;
        __syncthreads();
    }

    // sigmoid scores -> Sc (aliases dead limb planes; all reads done at last barrier)
    #pragma unroll
    for (int tt = 0; tt < 2; ++tt)
        #pragma unroll
        for (int et = 0; et < 2; ++et)
            #pragma unroll
            for (int r = 0; r < 4; ++r) {
                float logit = (float)md[tt][et][r];
                float s = 1.0f / (1.0f + expf(-logit));
                int t = wr * 32 + tt * 16 + g * 4 + r;
                int e = wc * 32 + et * 16 + l15;
                scf[t * 65 + e] = s;
            }
    __syncthreads();

    // grouped top-k, one token per active thread (64 tokens over 4 waves)
    if ((tid & 3) == 0) {
        const int t = tid >> 2;
        const float* sc = &scf[t * 65];
        float gs[8];
        #pragma unroll
        for (int gg = 0; gg < 8; ++gg) {
            float m1 = -1e30f, m2 = -1e30f;
            #pragma unroll
            for (int j = 0; j < 8; ++j) {
                float v = sc[gg * 8 + j] + bsf[gg * 8 + j];
                if (v > m1) { m2 = m1; m1 = v; }
                else if (v > m2) { m2 = v; }
            }
            gs[gg] = m1 + m2;
        }
        unsigned gmask = 0;
        for (int i = 0; i < 4; ++i) {
            float best = -1e30f; int bg = 0;
            for (int gg = 0; gg < 8; ++gg)
                if (!((gmask >> gg) & 1u) && gs[gg] > best) { best = gs[gg]; bg = gg; }
            gmask |= 1u << bg;
        }
        unsigned long long picked = 0ull;
        int   idxs[8];
        float wts[8];
        float wsum = 0.0f;
        for (int i = 0; i < 8; ++i) {
            float best = -1e30f; int bi = 0;
            for (int e = 0; e < 64; ++e) {
                if ((picked >> e) & 1ull) continue;
                float v = ((gmask >> (e >> 3)) & 1u) ? (sc[e] + bsf[e]) : 0.0f;
                if (v > best) { best = v; bi = e; }
            }
            picked |= 1ull << bi;
            idxs[i] = bi;
            wts[i] = sc[bi];
            wsum += sc[bi];
        }
        const float scale = RSCALE / (wsum + REPS);
        const size_t token = tb + t;
        #pragma unroll
        for (int i = 0; i < 8; ++i) {
            out[token * 8 + i] = (float)idxs[i];
            out[(size_t)NT * 8 + token * 8 + i] = wts[i] * scale;
        }
    }
}

extern "C" void kernel_launch(void* const* d_in, const int* in_sizes, int n_in,
                              void* d_out, int out_size, void* d_ws, size_t ws_size,
                              hipStream_t stream) {
    (void)in_sizes; (void)n_in; (void)out_size; (void)d_ws; (void)ws_size;
    const float* H = (const float*)d_in[0];
    const float* W = (const float*)d_in[1];
    const float* B = (const float*)d_in[2];
    float* out = (float*)d_out;
    prep_w_kernel<<<dim3(NCH), dim3(256), 0, stream>>>(W);
    router_kernel<<<dim3(NT / TOK), dim3(256), 0, stream>>>(H, B, out);
}